// Round 1
// baseline (7061.075 us; speedup 1.0000x reference)
//
#include <hip/hip_runtime.h>
#include <hip/hip_bf16.h>

// SimGCL / LightGCN 2-layer propagation.
//   deg[n]  = #edges with col==n
//   dis[n]  = deg>0 ? rsqrt(deg) : 0
//   w[e]    = dis[row[e]] * dis[col[e]]
//   emb1[c] = sum_e{col==c} x[row[e]]    * w[e]
//   emb2[c] = sum_e{col==c} emb1[row[e]] * w[e]
//   out     = (x + emb1 + emb2) / 3
//
// Round 0: correctness-first scatter-atomic baseline.
//   - 16 threads/edge, float4 per thread (coalesced 256B gather per edge)
//   - 4 scalar f32 atomicAdds per thread into the target row
//   - emb2 accumulated directly in d_out (memset to 0 first), final pass
//     rewrites d_out in place as (x + emb1 + d_out)/3.

#define N_NODES 150000
#define EMB_DIM 64

__global__ void deg_kernel(const int* __restrict__ cols,
                           float* __restrict__ deg, int E) {
    int e = blockIdx.x * blockDim.x + threadIdx.x;
    if (e < E) {
        atomicAdd(&deg[cols[e]], 1.0f);
    }
}

__global__ void dis_kernel(float* __restrict__ deg_dis, int n) {
    int i = blockIdx.x * blockDim.x + threadIdx.x;
    if (i < n) {
        float d = deg_dis[i];
        deg_dis[i] = (d > 0.0f) ? rsqrtf(d) : 0.0f;
    }
}

// One edge handled by 16 consecutive threads; thread c owns dims [4c, 4c+4).
__global__ void conv_kernel(const float* __restrict__ emb_in,
                            const int* __restrict__ rows,
                            const int* __restrict__ cols,
                            const float* __restrict__ dis,
                            float* __restrict__ emb_out, int E) {
    int tid = blockIdx.x * blockDim.x + threadIdx.x;
    int e = tid >> 4;
    if (e >= E) return;
    int c = tid & 15;

    int r  = rows[e];
    int cl = cols[e];
    float w = dis[r] * dis[cl];

    const float4 v = ((const float4*)(emb_in + (size_t)r * EMB_DIM))[c];
    float* dst = emb_out + (size_t)cl * EMB_DIM + c * 4;
    atomicAdd(dst + 0, v.x * w);
    atomicAdd(dst + 1, v.y * w);
    atomicAdd(dst + 2, v.z * w);
    atomicAdd(dst + 3, v.w * w);
}

// out = (x + emb1 + out) / 3, float4-vectorized, in place on d_out.
__global__ void final_kernel(const float* __restrict__ x,
                             const float* __restrict__ emb1,
                             float* __restrict__ out, int n4) {
    int i = blockIdx.x * blockDim.x + threadIdx.x;
    if (i >= n4) return;
    float4 a = ((const float4*)x)[i];
    float4 b = ((const float4*)emb1)[i];
    float4 c = ((float4*)out)[i];
    const float k = 1.0f / 3.0f;
    c.x = (a.x + b.x + c.x) * k;
    c.y = (a.y + b.y + c.y) * k;
    c.z = (a.z + b.z + c.z) * k;
    c.w = (a.w + b.w + c.w) * k;
    ((float4*)out)[i] = c;
}

extern "C" void kernel_launch(void* const* d_in, const int* in_sizes, int n_in,
                              void* d_out, int out_size, void* d_ws, size_t ws_size,
                              hipStream_t stream) {
    const float* x  = (const float*)d_in[0];
    const int*   ei = (const int*)d_in[1];
    const int E = in_sizes[1] / 2;
    const int N = in_sizes[0] / EMB_DIM;  // 150000

    const int* rows = ei;       // edge_index[0]
    const int* cols = ei + E;   // edge_index[1]

    // Workspace layout: [dis: N floats (padded to 150016)] [emb1: N*64 floats]
    float* dis  = (float*)d_ws;
    float* emb1 = dis + 150016;
    float* out  = (float*)d_out;

    hipMemsetAsync(dis,  0, (size_t)N * sizeof(float), stream);
    hipMemsetAsync(emb1, 0, (size_t)N * EMB_DIM * sizeof(float), stream);
    hipMemsetAsync(out,  0, (size_t)N * EMB_DIM * sizeof(float), stream);

    const int B = 256;
    deg_kernel<<<(E + B - 1) / B, B, 0, stream>>>(cols, dis, E);
    dis_kernel<<<(N + B - 1) / B, B, 0, stream>>>(dis, N);

    long long conv_threads = (long long)E * 16;
    int conv_blocks = (int)((conv_threads + B - 1) / B);
    // layer 1: x -> emb1
    conv_kernel<<<conv_blocks, B, 0, stream>>>(x, rows, cols, dis, emb1, E);
    // layer 2: emb1 -> out (accumulator)
    conv_kernel<<<conv_blocks, B, 0, stream>>>(emb1, rows, cols, dis, out, E);

    int n4 = N * EMB_DIM / 4;
    final_kernel<<<(n4 + B - 1) / B, B, 0, stream>>>(x, emb1, out, n4);
}

// Round 2
// 1343.762 us; speedup vs baseline: 5.2547x; 5.2547x over previous
//
#include <hip/hip_runtime.h>
#include <hip/hip_bf16.h>

// SimGCL / LightGCN 2-layer propagation — round 1: CSR + gather (no f32 atomics).
//
//   counts[n] = #edges with col==n        (int histogram)
//   dis[n]    = counts>0 ? rsqrt(counts) : 0
//   offsets   = exclusive_scan(counts)    (single-block hierarchical scan)
//   sorted edges: for e, pos=atomicAdd(cursor[col[e]]); src_s[pos]=row[e];
//                 w_s[pos]=dis[row]*dis[col]
//   agg: one wave per destination node, lane = dim (D=64):
//        acc = sum_{incident edges} w * emb_in[src*64 + lane]   (register acc,
//        coalesced 256B gather per edge, single coalesced store per node)
//   layer2 fused with final: out = (x + emb1 + acc)/3

#define EMB_DIM 64
#define SCAN_THREADS 1024

__global__ void hist_kernel(const int* __restrict__ cols,
                            int* __restrict__ counts, int E) {
    int e = blockIdx.x * blockDim.x + threadIdx.x;
    if (e < E) atomicAdd(&counts[cols[e]], 1);
}

__global__ void dis_kernel(const int* __restrict__ counts,
                           float* __restrict__ dis, int n) {
    int i = blockIdx.x * blockDim.x + threadIdx.x;
    if (i < n) {
        int c = counts[i];
        dis[i] = (c > 0) ? rsqrtf((float)c) : 0.0f;
    }
}

// Single-block exclusive scan over n counts -> offsets[0..n], cursor[0..n-1].
__global__ void scan_kernel(const int* __restrict__ counts,
                            int* __restrict__ offsets,
                            int* __restrict__ cursor, int n) {
    __shared__ int lds[SCAN_THREADS];
    const int tid = threadIdx.x;
    const int CH = (n + SCAN_THREADS - 1) / SCAN_THREADS;
    const int base = tid * CH;
    const int lim = min(base + CH, n);

    int sum = 0;
    for (int i = base; i < lim; ++i) sum += counts[i];
    lds[tid] = sum;
    __syncthreads();

    // Hillis-Steele inclusive scan in LDS
    for (int off = 1; off < SCAN_THREADS; off <<= 1) {
        int v = (tid >= off) ? lds[tid - off] : 0;
        __syncthreads();
        lds[tid] += v;
        __syncthreads();
    }
    int run = lds[tid] - sum;  // exclusive prefix of this chunk

    for (int i = base; i < lim; ++i) {
        offsets[i] = run;
        cursor[i] = run;
        run += counts[i];
    }
    if (tid == SCAN_THREADS - 1) offsets[n] = lds[SCAN_THREADS - 1];
}

__global__ void scatter_kernel(const int* __restrict__ rows,
                               const int* __restrict__ cols,
                               const float* __restrict__ dis,
                               int* __restrict__ cursor,
                               int* __restrict__ src_s,
                               float* __restrict__ w_s, int E) {
    int e = blockIdx.x * blockDim.x + threadIdx.x;
    if (e >= E) return;
    int r = rows[e];
    int c = cols[e];
    float w = dis[r] * dis[c];
    int pos = atomicAdd(&cursor[c], 1);
    src_s[pos] = r;
    w_s[pos] = w;
}

// One 64-lane wave per destination node; lane owns one embedding dim.
template <bool FINAL>
__global__ void agg_kernel(const float* __restrict__ emb_in,
                           const int* __restrict__ src_s,
                           const float* __restrict__ w_s,
                           const int* __restrict__ offsets,
                           const float* __restrict__ x,     // FINAL only
                           const float* __restrict__ emb1,  // FINAL only
                           float* __restrict__ out, int n) {
    int wave = (blockIdx.x * blockDim.x + threadIdx.x) >> 6;
    int lane = threadIdx.x & 63;
    if (wave >= n) return;

    int s = offsets[wave];
    int e = offsets[wave + 1];
    float acc = 0.0f;

    for (int b = s; b < e; b += 64) {
        int cnt = min(64, e - b);
        int msrc = 0;
        float mw = 0.0f;
        if (lane < cnt) {
            msrc = src_s[b + lane];
            mw = w_s[b + lane];
        }
#pragma unroll 4
        for (int j = 0; j < cnt; ++j) {
            int sj = __shfl(msrc, j);
            float wj = __shfl(mw, j);
            acc += wj * emb_in[(size_t)sj * EMB_DIM + lane];
        }
    }

    size_t o = (size_t)wave * EMB_DIM + lane;
    if (FINAL) {
        out[o] = (x[o] + emb1[o] + acc) * (1.0f / 3.0f);
    } else {
        out[o] = acc;
    }
}

extern "C" void kernel_launch(void* const* d_in, const int* in_sizes, int n_in,
                              void* d_out, int out_size, void* d_ws, size_t ws_size,
                              hipStream_t stream) {
    const float* x  = (const float*)d_in[0];
    const int*   ei = (const int*)d_in[1];
    const int E = in_sizes[1] / 2;
    const int N = in_sizes[0] / EMB_DIM;  // 150000

    const int* rows = ei;       // edge_index[0]
    const int* cols = ei + E;   // edge_index[1]

    // Workspace layout (4-byte units), PAD keeps 256B alignment:
    const int PAD = 150080;  // >= N+1, multiple of 64
    int*   counts  = (int*)d_ws;
    float* dis     = (float*)(counts + PAD);
    int*   offsets = (int*)(dis + PAD);       // [N+1]
    int*   cursor  = offsets + PAD;
    int*   src_s   = cursor + PAD;            // [E]
    float* w_s     = (float*)(src_s + E);     // [E]
    float* emb1    = w_s + E;                 // [N*64]
    float* out     = (float*)d_out;

    const int B = 256;
    hipMemsetAsync(counts, 0, (size_t)N * sizeof(int), stream);

    hist_kernel<<<(E + B - 1) / B, B, 0, stream>>>(cols, counts, E);
    dis_kernel<<<(N + B - 1) / B, B, 0, stream>>>(counts, dis, N);
    scan_kernel<<<1, SCAN_THREADS, 0, stream>>>(counts, offsets, cursor, N);
    scatter_kernel<<<(E + B - 1) / B, B, 0, stream>>>(rows, cols, dis, cursor,
                                                      src_s, w_s, E);

    int waves_per_block = B / 64;
    int agg_blocks = (N + waves_per_block - 1) / waves_per_block;
    // layer 1: x -> emb1
    agg_kernel<false><<<agg_blocks, B, 0, stream>>>(x, src_s, w_s, offsets,
                                                    nullptr, nullptr, emb1, N);
    // layer 2 + final: out = (x + emb1 + agg(emb1)) / 3
    agg_kernel<true><<<agg_blocks, B, 0, stream>>>(emb1, src_s, w_s, offsets,
                                                   x, emb1, out, N);
}

// Round 3
// 906.001 us; speedup vs baseline: 7.7937x; 1.4832x over previous
//
#include <hip/hip_runtime.h>
#include <hip/hip_bf16.h>

// SimGCL / LightGCN 2-layer propagation — round 2.
//   r1 -> r2: parallel 3-kernel scan (was single-block, 336us on one CU);
//             (src,w) packed into int2 (halves random-write cachelines in
//             scatter, one 8B metadata load in agg).

#define EMB_DIM 64
#define TILE 1024  // counts per scan tile (256 threads x 4)

__global__ void hist_kernel(const int* __restrict__ cols,
                            int* __restrict__ counts, int E) {
    int e = blockIdx.x * blockDim.x + threadIdx.x;
    if (e < E) atomicAdd(&counts[cols[e]], 1);
}

__global__ void dis_kernel(const int* __restrict__ counts,
                           float* __restrict__ dis, int n) {
    int i = blockIdx.x * blockDim.x + threadIdx.x;
    if (i < n) {
        int c = counts[i];
        dis[i] = (c > 0) ? rsqrtf((float)c) : 0.0f;
    }
}

// (a) per-tile sums: block b reduces counts[b*1024 .. b*1024+1023]
__global__ void tile_sum_kernel(const int* __restrict__ counts,
                                int* __restrict__ tile_sums, int n) {
    __shared__ int red[4];
    int t = threadIdx.x;
    int base = blockIdx.x * TILE + t * 4;
    int s = 0;
    if (base + 3 < n) {
        int4 v = *(const int4*)(counts + base);
        s = v.x + v.y + v.z + v.w;
    } else {
        for (int i = 0; i < 4; ++i)
            if (base + i < n) s += counts[base + i];
    }
    for (int off = 32; off; off >>= 1) s += __shfl_down(s, off);
    if ((t & 63) == 0) red[t >> 6] = s;
    __syncthreads();
    if (t == 0)
        tile_sums[blockIdx.x] = red[0] + red[1] + red[2] + red[3];
}

// (b) scan the tile sums (nb <= 256) -> exclusive tile offsets; total -> offsets[n]
__global__ void tile_scan_kernel(const int* __restrict__ tile_sums,
                                 int* __restrict__ tile_off,
                                 int* __restrict__ offsets, int nb, int n) {
    __shared__ int lds[256];
    int t = threadIdx.x;
    int v = (t < nb) ? tile_sums[t] : 0;
    lds[t] = v;
    __syncthreads();
    for (int off = 1; off < 256; off <<= 1) {
        int u = (t >= off) ? lds[t - off] : 0;
        __syncthreads();
        lds[t] += u;
        __syncthreads();
    }
    if (t < nb) tile_off[t] = lds[t] - v;
    if (t == 255) offsets[n] = lds[255];
}

// (c) re-scan each tile with its offset -> offsets[i], cursor[i]
__global__ void rescan_kernel(const int* __restrict__ counts,
                              const int* __restrict__ tile_off,
                              int* __restrict__ offsets,
                              int* __restrict__ cursor, int n) {
    __shared__ int lds[256];
    int t = threadIdx.x;
    int base = blockIdx.x * TILE + t * 4;
    int c0 = 0, c1 = 0, c2 = 0, c3 = 0;
    if (base + 3 < n) {
        int4 v = *(const int4*)(counts + base);
        c0 = v.x; c1 = v.y; c2 = v.z; c3 = v.w;
    } else {
        if (base + 0 < n) c0 = counts[base + 0];
        if (base + 1 < n) c1 = counts[base + 1];
        if (base + 2 < n) c2 = counts[base + 2];
        if (base + 3 < n) c3 = counts[base + 3];
    }
    int s = c0 + c1 + c2 + c3;
    lds[t] = s;
    __syncthreads();
    for (int off = 1; off < 256; off <<= 1) {
        int u = (t >= off) ? lds[t - off] : 0;
        __syncthreads();
        lds[t] += u;
        __syncthreads();
    }
    int run = tile_off[blockIdx.x] + lds[t] - s;
    if (base + 0 < n) { offsets[base + 0] = run; cursor[base + 0] = run; run += c0; }
    if (base + 1 < n) { offsets[base + 1] = run; cursor[base + 1] = run; run += c1; }
    if (base + 2 < n) { offsets[base + 2] = run; cursor[base + 2] = run; run += c2; }
    if (base + 3 < n) { offsets[base + 3] = run; cursor[base + 3] = run; run += c3; }
}

__global__ void scatter_kernel(const int* __restrict__ rows,
                               const int* __restrict__ cols,
                               const float* __restrict__ dis,
                               int* __restrict__ cursor,
                               int2* __restrict__ edata, int E) {
    int e = blockIdx.x * blockDim.x + threadIdx.x;
    if (e >= E) return;
    int r = rows[e];
    int c = cols[e];
    float w = dis[r] * dis[c];
    int pos = atomicAdd(&cursor[c], 1);
    edata[pos] = make_int2(r, __float_as_int(w));
}

// One 64-lane wave per destination node; lane owns one embedding dim.
// FINAL: out = (x + emb_in + acc)/3   (emb_in == emb1 in the final pass)
template <bool FINAL>
__global__ void agg_kernel(const float* __restrict__ emb_in,
                           const int2* __restrict__ edata,
                           const int* __restrict__ offsets,
                           const float* __restrict__ x,  // FINAL only
                           float* __restrict__ out, int n) {
    int wave = (blockIdx.x * blockDim.x + threadIdx.x) >> 6;
    int lane = threadIdx.x & 63;
    if (wave >= n) return;

    int s = offsets[wave];
    int e = offsets[wave + 1];
    float acc = 0.0f;

    for (int b = s; b < e; b += 64) {
        int cnt = min(64, e - b);
        int msrc = 0;
        float mw = 0.0f;
        if (lane < cnt) {
            int2 md = edata[b + lane];
            msrc = md.x;
            mw = __int_as_float(md.y);
        }
#pragma unroll 4
        for (int j = 0; j < cnt; ++j) {
            int sj = __shfl(msrc, j);
            float wj = __shfl(mw, j);
            acc += wj * emb_in[(size_t)sj * EMB_DIM + lane];
        }
    }

    size_t o = (size_t)wave * EMB_DIM + lane;
    if (FINAL) {
        out[o] = (x[o] + emb_in[o] + acc) * (1.0f / 3.0f);
    } else {
        out[o] = acc;
    }
}

extern "C" void kernel_launch(void* const* d_in, const int* in_sizes, int n_in,
                              void* d_out, int out_size, void* d_ws, size_t ws_size,
                              hipStream_t stream) {
    const float* x  = (const float*)d_in[0];
    const int*   ei = (const int*)d_in[1];
    const int E = in_sizes[1] / 2;
    const int N = in_sizes[0] / EMB_DIM;  // 150000

    const int* rows = ei;       // edge_index[0]
    const int* cols = ei + E;   // edge_index[1]

    // Workspace layout (ints), PAD keeps 256B alignment:
    const int PAD = 150080;  // >= N+1, multiple of 64
    int*   counts   = (int*)d_ws;
    float* dis      = (float*)(counts + PAD);
    int*   offsets  = (int*)(dis + PAD);      // [N+1]
    int*   cursor   = offsets + PAD;
    int*   tsum     = cursor + PAD;           // [<=256]
    int*   toff     = tsum + 256;             // [<=256]
    int2*  edata    = (int2*)(toff + 256);    // [E] packed (src, w)
    float* emb1     = (float*)(edata + E);    // [N*64]
    float* out      = (float*)d_out;

    const int B = 256;
    const int nb = (N + TILE - 1) / TILE;  // 147 scan tiles

    hipMemsetAsync(counts, 0, (size_t)N * sizeof(int), stream);

    hist_kernel<<<(E + B - 1) / B, B, 0, stream>>>(cols, counts, E);
    dis_kernel<<<(N + B - 1) / B, B, 0, stream>>>(counts, dis, N);
    tile_sum_kernel<<<nb, B, 0, stream>>>(counts, tsum, N);
    tile_scan_kernel<<<1, B, 0, stream>>>(tsum, toff, offsets, nb, N);
    rescan_kernel<<<nb, B, 0, stream>>>(counts, toff, offsets, cursor, N);
    scatter_kernel<<<(E + B - 1) / B, B, 0, stream>>>(rows, cols, dis, cursor,
                                                      edata, E);

    int waves_per_block = B / 64;
    int agg_blocks = (N + waves_per_block - 1) / waves_per_block;
    // layer 1: x -> emb1
    agg_kernel<false><<<agg_blocks, B, 0, stream>>>(x, edata, offsets,
                                                    nullptr, emb1, N);
    // layer 2 + final: out = (x + emb1 + agg(emb1)) / 3
    agg_kernel<true><<<agg_blocks, B, 0, stream>>>(emb1, edata, offsets,
                                                   x, out, N);
}

// Round 4
// 646.490 us; speedup vs baseline: 10.9222x; 1.4014x over previous
//
#include <hip/hip_runtime.h>
#include <hip/hip_bf16.h>

// SimGCL / LightGCN 2-layer propagation — round 3.
//   r2 -> r3: agg was gather-latency-bound (242us, 27% HBM, 22% VALU).
//   - agg restructured: wave = 8 subgroups x 8 lanes, 8 edges in flight
//     per wave (was 1), no inner-loop shuffles (metadata loaded per-sub).
//   - gather operands in bf16: x converted once, emb1 stored bf16 ->
//     128B/edge instead of 256B. x still added in fp32 in the final sum.

#define EMB_DIM 64
#define TILE 1024  // counts per scan tile (256 threads x 4)

__device__ __forceinline__ float bf_lo(unsigned int q) { return __uint_as_float(q << 16); }
__device__ __forceinline__ float bf_hi(unsigned int q) { return __uint_as_float(q & 0xffff0000u); }
__device__ __forceinline__ unsigned int f2bf(float f) {  // RNE
    unsigned int u = __float_as_uint(f);
    return (u + 0x7fffu + ((u >> 16) & 1u)) >> 16;
}

__global__ void hist_kernel(const int* __restrict__ cols,
                            int* __restrict__ counts, int E) {
    int e = blockIdx.x * blockDim.x + threadIdx.x;
    if (e < E) atomicAdd(&counts[cols[e]], 1);
}

__global__ void dis_kernel(const int* __restrict__ counts,
                           float* __restrict__ dis, int n) {
    int i = blockIdx.x * blockDim.x + threadIdx.x;
    if (i < n) {
        int c = counts[i];
        dis[i] = (c > 0) ? rsqrtf((float)c) : 0.0f;
    }
}

// fp32 -> bf16 (RNE), 4 floats per thread
__global__ void tobf_kernel(const float* __restrict__ x,
                            unsigned short* __restrict__ xb, int n4) {
    int i = blockIdx.x * blockDim.x + threadIdx.x;
    if (i >= n4) return;
    float4 v = ((const float4*)x)[i];
    uint2 o;
    o.x = f2bf(v.x) | (f2bf(v.y) << 16);
    o.y = f2bf(v.z) | (f2bf(v.w) << 16);
    ((uint2*)xb)[i] = o;
}

// (a) per-tile sums
__global__ void tile_sum_kernel(const int* __restrict__ counts,
                                int* __restrict__ tile_sums, int n) {
    __shared__ int red[4];
    int t = threadIdx.x;
    int base = blockIdx.x * TILE + t * 4;
    int s = 0;
    if (base + 3 < n) {
        int4 v = *(const int4*)(counts + base);
        s = v.x + v.y + v.z + v.w;
    } else {
        for (int i = 0; i < 4; ++i)
            if (base + i < n) s += counts[base + i];
    }
    for (int off = 32; off; off >>= 1) s += __shfl_down(s, off);
    if ((t & 63) == 0) red[t >> 6] = s;
    __syncthreads();
    if (t == 0)
        tile_sums[blockIdx.x] = red[0] + red[1] + red[2] + red[3];
}

// (b) scan tile sums (nb <= 256)
__global__ void tile_scan_kernel(const int* __restrict__ tile_sums,
                                 int* __restrict__ tile_off,
                                 int* __restrict__ offsets, int nb, int n) {
    __shared__ int lds[256];
    int t = threadIdx.x;
    int v = (t < nb) ? tile_sums[t] : 0;
    lds[t] = v;
    __syncthreads();
    for (int off = 1; off < 256; off <<= 1) {
        int u = (t >= off) ? lds[t - off] : 0;
        __syncthreads();
        lds[t] += u;
        __syncthreads();
    }
    if (t < nb) tile_off[t] = lds[t] - v;
    if (t == 255) offsets[n] = lds[255];
}

// (c) re-scan each tile -> offsets, cursor
__global__ void rescan_kernel(const int* __restrict__ counts,
                              const int* __restrict__ tile_off,
                              int* __restrict__ offsets,
                              int* __restrict__ cursor, int n) {
    __shared__ int lds[256];
    int t = threadIdx.x;
    int base = blockIdx.x * TILE + t * 4;
    int c0 = 0, c1 = 0, c2 = 0, c3 = 0;
    if (base + 3 < n) {
        int4 v = *(const int4*)(counts + base);
        c0 = v.x; c1 = v.y; c2 = v.z; c3 = v.w;
    } else {
        if (base + 0 < n) c0 = counts[base + 0];
        if (base + 1 < n) c1 = counts[base + 1];
        if (base + 2 < n) c2 = counts[base + 2];
        if (base + 3 < n) c3 = counts[base + 3];
    }
    int s = c0 + c1 + c2 + c3;
    lds[t] = s;
    __syncthreads();
    for (int off = 1; off < 256; off <<= 1) {
        int u = (t >= off) ? lds[t - off] : 0;
        __syncthreads();
        lds[t] += u;
        __syncthreads();
    }
    int run = tile_off[blockIdx.x] + lds[t] - s;
    if (base + 0 < n) { offsets[base + 0] = run; cursor[base + 0] = run; run += c0; }
    if (base + 1 < n) { offsets[base + 1] = run; cursor[base + 1] = run; run += c1; }
    if (base + 2 < n) { offsets[base + 2] = run; cursor[base + 2] = run; run += c2; }
    if (base + 3 < n) { offsets[base + 3] = run; cursor[base + 3] = run; run += c3; }
}

__global__ void scatter_kernel(const int* __restrict__ rows,
                               const int* __restrict__ cols,
                               const float* __restrict__ dis,
                               int* __restrict__ cursor,
                               int2* __restrict__ edata, int E) {
    int e = blockIdx.x * blockDim.x + threadIdx.x;
    if (e >= E) return;
    int r = rows[e];
    int c = cols[e];
    float w = dis[r] * dis[c];
    int pos = atomicAdd(&cursor[c], 1);
    edata[pos] = make_int2(r, __float_as_int(w));
}

// Wave = 8 subgroups x 8 lanes. sub owns one edge per iteration (8 edges in
// flight); lane owns dims [(lane&7)*8, +8) in fp32 acc. Gather is bf16
// (16B/lane). Cross-sub reduce via shfl_xor; sub 0 stores.
template <bool FINAL>
__global__ void agg_kernel(const unsigned short* __restrict__ embb,  // bf16 [N*64]
                           const int2* __restrict__ edata,
                           const int* __restrict__ offsets,
                           const float* __restrict__ x,          // FINAL only
                           unsigned short* __restrict__ outb,    // !FINAL
                           float* __restrict__ outf,             // FINAL
                           int n) {
    int wave = (blockIdx.x * blockDim.x + threadIdx.x) >> 6;
    int lane = threadIdx.x & 63;
    if (wave >= n) return;
    int sub  = lane >> 3;
    int dimo = (lane & 7) * 8;

    int s = offsets[wave];
    int e = offsets[wave + 1];

    float acc[8] = {0, 0, 0, 0, 0, 0, 0, 0};

    for (int b = s; b < e; b += 8) {
        int idx = b + sub;
        float w = 0.0f;
        int src = 0;
        if (idx < e) {
            int2 md = edata[idx];
            src = md.x;
            w = __int_as_float(md.y);
        }
        if (w != 0.0f) {
            uint4 q = *(const uint4*)(embb + (size_t)src * EMB_DIM + dimo);
            acc[0] += w * bf_lo(q.x);
            acc[1] += w * bf_hi(q.x);
            acc[2] += w * bf_lo(q.y);
            acc[3] += w * bf_hi(q.y);
            acc[4] += w * bf_lo(q.z);
            acc[5] += w * bf_hi(q.z);
            acc[6] += w * bf_lo(q.w);
            acc[7] += w * bf_hi(q.w);
        }
    }

#pragma unroll
    for (int k = 0; k < 8; ++k) {
        acc[k] += __shfl_xor(acc[k], 8);
        acc[k] += __shfl_xor(acc[k], 16);
        acc[k] += __shfl_xor(acc[k], 32);
    }

    if (sub == 0) {
        size_t o = (size_t)wave * EMB_DIM + dimo;
        if (FINAL) {
            float4 xa = *(const float4*)(x + o);
            float4 xc = *(const float4*)(x + o + 4);
            uint4 q = *(const uint4*)(embb + o);  // emb1 (bf16)
            const float k3 = 1.0f / 3.0f;
            float4 r0, r1;
            r0.x = (xa.x + bf_lo(q.x) + acc[0]) * k3;
            r0.y = (xa.y + bf_hi(q.x) + acc[1]) * k3;
            r0.z = (xa.z + bf_lo(q.y) + acc[2]) * k3;
            r0.w = (xa.w + bf_hi(q.y) + acc[3]) * k3;
            r1.x = (xc.x + bf_lo(q.z) + acc[4]) * k3;
            r1.y = (xc.y + bf_hi(q.z) + acc[5]) * k3;
            r1.z = (xc.z + bf_lo(q.w) + acc[6]) * k3;
            r1.w = (xc.w + bf_hi(q.w) + acc[7]) * k3;
            *(float4*)(outf + o) = r0;
            *(float4*)(outf + o + 4) = r1;
        } else {
            uint4 q;
            q.x = f2bf(acc[0]) | (f2bf(acc[1]) << 16);
            q.y = f2bf(acc[2]) | (f2bf(acc[3]) << 16);
            q.z = f2bf(acc[4]) | (f2bf(acc[5]) << 16);
            q.w = f2bf(acc[6]) | (f2bf(acc[7]) << 16);
            *(uint4*)(outb + o) = q;
        }
    }
}

extern "C" void kernel_launch(void* const* d_in, const int* in_sizes, int n_in,
                              void* d_out, int out_size, void* d_ws, size_t ws_size,
                              hipStream_t stream) {
    const float* x  = (const float*)d_in[0];
    const int*   ei = (const int*)d_in[1];
    const int E = in_sizes[1] / 2;
    const int N = in_sizes[0] / EMB_DIM;  // 150000

    const int* rows = ei;       // edge_index[0]
    const int* cols = ei + E;   // edge_index[1]

    // Workspace layout (ints), PAD keeps 256B alignment:
    const int PAD = 150080;  // >= N+1, multiple of 64
    int*   counts   = (int*)d_ws;
    float* dis      = (float*)(counts + PAD);
    int*   offsets  = (int*)(dis + PAD);      // [N+1]
    int*   cursor   = offsets + PAD;
    int*   tsum     = cursor + PAD;           // [<=256]
    int*   toff     = tsum + 256;             // [<=256]
    int2*  edata    = (int2*)(toff + 256);    // [E] packed (src, w)
    unsigned short* xb    = (unsigned short*)(edata + E);  // bf16 x [N*64]
    unsigned short* emb1b = xb + (size_t)N * EMB_DIM;      // bf16 emb1 [N*64]
    float* out      = (float*)d_out;

    const int B = 256;
    const int nb = (N + TILE - 1) / TILE;  // 147 scan tiles

    hipMemsetAsync(counts, 0, (size_t)N * sizeof(int), stream);

    hist_kernel<<<(E + B - 1) / B, B, 0, stream>>>(cols, counts, E);
    dis_kernel<<<(N + B - 1) / B, B, 0, stream>>>(counts, dis, N);
    tile_sum_kernel<<<nb, B, 0, stream>>>(counts, tsum, N);
    tile_scan_kernel<<<1, B, 0, stream>>>(tsum, toff, offsets, nb, N);
    rescan_kernel<<<nb, B, 0, stream>>>(counts, toff, offsets, cursor, N);
    scatter_kernel<<<(E + B - 1) / B, B, 0, stream>>>(rows, cols, dis, cursor,
                                                      edata, E);
    int n4 = N * EMB_DIM / 4;
    tobf_kernel<<<(n4 + B - 1) / B, B, 0, stream>>>(x, xb, n4);

    int waves_per_block = B / 64;
    int agg_blocks = (N + waves_per_block - 1) / waves_per_block;
    // layer 1: xb -> emb1b (bf16)
    agg_kernel<false><<<agg_blocks, B, 0, stream>>>(xb, edata, offsets,
                                                    nullptr, emb1b, nullptr, N);
    // layer 2 + final: out = (x + emb1 + agg(emb1b)) / 3
    agg_kernel<true><<<agg_blocks, B, 0, stream>>>(emb1b, edata, offsets,
                                                   x, nullptr, out, N);
}

// Round 5
// 414.961 us; speedup vs baseline: 17.0162x; 1.5580x over previous
//
#include <hip/hip_runtime.h>
#include <hip/hip_bf16.h>

// SimGCL / LightGCN 2-layer propagation — round 4.
//   r3 -> r4: scatter_kernel wrote 249 MB for 32 MB payload (random 8B
//   writes, cross-XCD partial-line writebacks) + 4M global atomics.
//   Replaced with a 2-phase bucket sort (293 buckets of 512 cols):
//     A bucket_hist:    per-block LDS hist -> blkcnt[bucket][blk]
//     B cursor_scan:    exclusive scan of blkcnt (in place) -> run cursors
//     C bucket_scatter: partition pass, contiguous ~224B runs per bucket
//     D bucket_finalize: per-bucket exact counting sort (LDS), emits
//                        dis[], offsets[], col-sorted src[] (4B/edge).
//   Algebraic refactor removes per-edge weights entirely:
//     y = dis*x (bf16);  emb1[c] = dis[c]*sum y[src];  z[c] = dis[c]*emb1[c]
//     emb2[c] = dis[c]*sum z[src];  emb1 reconstructed as z/dis in final.
//   No global atomics, no memsets anywhere.

#define EMB_DIM 64
#define BUCKET_BITS 9
#define BUCKET_SZ 512
#define EPB 16384   // edges per partition block
#define NBMAX 512   // LDS capacity for bucket counters (NB = 293 actual)

__device__ __forceinline__ float bf_lo(unsigned int q) { return __uint_as_float(q << 16); }
__device__ __forceinline__ float bf_hi(unsigned int q) { return __uint_as_float(q & 0xffff0000u); }
__device__ __forceinline__ unsigned int f2bf(float f) {  // RNE
    unsigned int u = __float_as_uint(f);
    return (u + 0x7fffu + ((u >> 16) & 1u)) >> 16;
}

// (A) per-block bucket histogram
__global__ void bucket_hist(const int* __restrict__ cols,
                            int* __restrict__ blkcnt, int E, int NB, int NBLK) {
    __shared__ int lh[NBMAX];
    int blk = blockIdx.x, t = threadIdx.x;
    for (int b = t; b < NB; b += blockDim.x) lh[b] = 0;
    __syncthreads();
    int start = blk * EPB, end = min(start + EPB, E);
    for (int i = start + t; i < end; i += blockDim.x)
        atomicAdd(&lh[cols[i] >> BUCKET_BITS], 1);
    __syncthreads();
    for (int b = t; b < NB; b += blockDim.x)
        blkcnt[b * NBLK + blk] = lh[b];
}

// (B) exclusive scan of blkcnt[M] in place (single block, vectorized);
//     also writes offsets[N] = E.
__global__ void cursor_scan(int* __restrict__ blkcnt,
                            int* __restrict__ offsets, int M, int N, int E) {
    __shared__ int lds[1024];
    int t = threadIdx.x;
    int M4 = (M + 3) >> 2;
    int CH = (M4 + 1023) >> 10;  // int4s per thread
    int base4 = t * CH;

    int sum = 0;
    for (int k = 0; k < CH; ++k) {
        int idx = (base4 + k) * 4;
        if (idx >= M) break;
        if (idx + 3 < M) {
            int4 v = *(const int4*)(blkcnt + idx);
            sum += v.x + v.y + v.z + v.w;
        } else {
            for (int j = idx; j < M; ++j) sum += blkcnt[j];
        }
    }
    lds[t] = sum;
    __syncthreads();
    for (int off = 1; off < 1024; off <<= 1) {
        int u = (t >= off) ? lds[t - off] : 0;
        __syncthreads();
        lds[t] += u;
        __syncthreads();
    }
    int run = lds[t] - sum;
    for (int k = 0; k < CH; ++k) {
        int idx = (base4 + k) * 4;
        if (idx >= M) break;
        if (idx + 3 < M) {
            int4 v = *(const int4*)(blkcnt + idx);
            int4 o;
            o.x = run; run += v.x;
            o.y = run; run += v.y;
            o.z = run; run += v.z;
            o.w = run; run += v.w;
            *(int4*)(blkcnt + idx) = o;
        } else {
            for (int j = idx; j < M; ++j) {
                int v = blkcnt[j];
                blkcnt[j] = run;
                run += v;
            }
        }
    }
    if (t == 0) offsets[N] = E;
}

// (C) partition pass: write packed (src | lcol<<18) into bucket runs
__global__ void bucket_scatter(const int* __restrict__ rows,
                               const int* __restrict__ cols,
                               const int* __restrict__ cursor,
                               unsigned int* __restrict__ pairs,
                               int E, int NB, int NBLK) {
    __shared__ int lcur[NBMAX];
    __shared__ int lrank[NBMAX];
    int blk = blockIdx.x, t = threadIdx.x;
    for (int b = t; b < NB; b += blockDim.x) {
        lcur[b] = cursor[b * NBLK + blk];
        lrank[b] = 0;
    }
    __syncthreads();
    int start = blk * EPB, end = min(start + EPB, E);
    for (int i = start + t; i < end; i += blockDim.x) {
        int c = cols[i];
        int r = rows[i];
        int b = c >> BUCKET_BITS;
        int rk = atomicAdd(&lrank[b], 1);
        pairs[lcur[b] + rk] = (unsigned)r | ((unsigned)(c & (BUCKET_SZ - 1)) << 18);
    }
}

// (D) per-bucket finalize: exact counting sort by col within bucket;
//     emits dis[], offsets[], and col-sorted src -> edata (4B/edge).
__global__ void bucket_finalize(const unsigned int* __restrict__ pairs,
                                const int* __restrict__ cursor,
                                int* __restrict__ edata,
                                int* __restrict__ offsets,
                                float* __restrict__ dis,
                                int N, int E, int NB, int NBLK) {
    __shared__ int ccnt[BUCKET_SZ];
    __shared__ int cexc[BUCKET_SZ];
    __shared__ int sc[1024];
    int b = blockIdx.x, t = threadIdx.x;
    int base = cursor[b * NBLK];
    int end = (b + 1 < NB) ? cursor[(b + 1) * NBLK] : E;
    int col0 = b << BUCKET_BITS;
    int ncols = min(BUCKET_SZ, N - col0);

    if (t < BUCKET_SZ) ccnt[t] = 0;
    __syncthreads();
    for (int i = base + t; i < end; i += blockDim.x)
        atomicAdd(&ccnt[pairs[i] >> 18], 1);
    __syncthreads();

    int v = (t < BUCKET_SZ) ? ccnt[t] : 0;
    sc[t] = v;
    __syncthreads();
    for (int off = 1; off < 1024; off <<= 1) {
        int u = (t >= off) ? sc[t - off] : 0;
        __syncthreads();
        sc[t] += u;
        __syncthreads();
    }
    if (t < BUCKET_SZ) cexc[t] = sc[t] - v;
    __syncthreads();

    if (t < ncols) {
        int c = ccnt[t];
        offsets[col0 + t] = base + cexc[t];
        dis[col0 + t] = (c > 0) ? rsqrtf((float)c) : 0.0f;
    }
    // reuse sc[0..511] as rank counters
    if (t < BUCKET_SZ) sc[t] = 0;
    __syncthreads();
    for (int i = base + t; i < end; i += blockDim.x) {
        unsigned p = pairs[i];
        int lc = p >> 18;
        int src = p & 0x3FFFF;
        int rk = atomicAdd(&sc[lc], 1);
        edata[base + cexc[lc] + rk] = src;
    }
}

// y = dis * x, stored bf16 (RNE). 4 floats/thread; 16 threads per node row.
__global__ void toy_kernel(const float* __restrict__ x,
                           const float* __restrict__ dis,
                           unsigned short* __restrict__ yb, int n4) {
    int i = blockIdx.x * blockDim.x + threadIdx.x;
    if (i >= n4) return;
    float d = dis[i >> 4];
    float4 v = ((const float4*)x)[i];
    uint2 o;
    o.x = f2bf(v.x * d) | (f2bf(v.y * d) << 16);
    o.y = f2bf(v.z * d) | (f2bf(v.w * d) << 16);
    ((uint2*)yb)[i] = o;
}

// Wave = 8 subgroups x 8 lanes; sub owns one edge/iter (8 edges in flight);
// lane accumulates 8 dims fp32 from bf16 gathers (no per-edge weight).
// !FINAL (layer 1, embb = yb):  z[c] = dis[c]^2 * acc  -> bf16 zb
//  FINAL (layer 2, embb = zb):  out = (x + z/dis + dis*acc)/3
template <bool FINAL>
__global__ void agg_kernel(const unsigned short* __restrict__ embb,
                           const int* __restrict__ edata,
                           const int* __restrict__ offsets,
                           const float* __restrict__ dis,
                           const float* __restrict__ x,        // FINAL only
                           unsigned short* __restrict__ outb,  // !FINAL
                           float* __restrict__ outf,           // FINAL
                           int n) {
    int wave = (blockIdx.x * blockDim.x + threadIdx.x) >> 6;
    int lane = threadIdx.x & 63;
    if (wave >= n) return;
    int sub = lane >> 3;
    int dimo = (lane & 7) * 8;

    int s = offsets[wave];
    int e = offsets[wave + 1];

    float acc[8] = {0, 0, 0, 0, 0, 0, 0, 0};

    for (int b = s; b < e; b += 8) {
        int idx = b + sub;
        if (idx < e) {
            int src = edata[idx];
            uint4 q = *(const uint4*)(embb + (size_t)src * EMB_DIM + dimo);
            acc[0] += bf_lo(q.x);
            acc[1] += bf_hi(q.x);
            acc[2] += bf_lo(q.y);
            acc[3] += bf_hi(q.y);
            acc[4] += bf_lo(q.z);
            acc[5] += bf_hi(q.z);
            acc[6] += bf_lo(q.w);
            acc[7] += bf_hi(q.w);
        }
    }

#pragma unroll
    for (int k = 0; k < 8; ++k) {
        acc[k] += __shfl_xor(acc[k], 8);
        acc[k] += __shfl_xor(acc[k], 16);
        acc[k] += __shfl_xor(acc[k], 32);
    }

    if (sub == 0) {
        float dc = dis[wave];
        size_t o = (size_t)wave * EMB_DIM + dimo;
        if (FINAL) {
            float rd = (dc > 0.0f) ? 1.0f / dc : 0.0f;  // emb1 = z * rd
            float4 xa = *(const float4*)(x + o);
            float4 xc = *(const float4*)(x + o + 4);
            uint4 qz = *(const uint4*)(embb + o);  // own z (bf16)
            const float k3 = 1.0f / 3.0f;
            float4 r0, r1;
            r0.x = (xa.x + bf_lo(qz.x) * rd + dc * acc[0]) * k3;
            r0.y = (xa.y + bf_hi(qz.x) * rd + dc * acc[1]) * k3;
            r0.z = (xa.z + bf_lo(qz.y) * rd + dc * acc[2]) * k3;
            r0.w = (xa.w + bf_hi(qz.y) * rd + dc * acc[3]) * k3;
            r1.x = (xc.x + bf_lo(qz.z) * rd + dc * acc[4]) * k3;
            r1.y = (xc.y + bf_hi(qz.z) * rd + dc * acc[5]) * k3;
            r1.z = (xc.z + bf_lo(qz.w) * rd + dc * acc[6]) * k3;
            r1.w = (xc.w + bf_hi(qz.w) * rd + dc * acc[7]) * k3;
            *(float4*)(outf + o) = r0;
            *(float4*)(outf + o + 4) = r1;
        } else {
            float zs = dc * dc;  // z = dis^2 * acc
            uint4 q;
            q.x = f2bf(zs * acc[0]) | (f2bf(zs * acc[1]) << 16);
            q.y = f2bf(zs * acc[2]) | (f2bf(zs * acc[3]) << 16);
            q.z = f2bf(zs * acc[4]) | (f2bf(zs * acc[5]) << 16);
            q.w = f2bf(zs * acc[6]) | (f2bf(zs * acc[7]) << 16);
            *(uint4*)(outb + o) = q;
        }
    }
}

extern "C" void kernel_launch(void* const* d_in, const int* in_sizes, int n_in,
                              void* d_out, int out_size, void* d_ws, size_t ws_size,
                              hipStream_t stream) {
    const float* x  = (const float*)d_in[0];
    const int*   ei = (const int*)d_in[1];
    const int E = in_sizes[1] / 2;
    const int N = in_sizes[0] / EMB_DIM;  // 150000

    const int* rows = ei;       // edge_index[0]
    const int* cols = ei + E;   // edge_index[1]

    const int NB = (N + BUCKET_SZ - 1) >> BUCKET_BITS;  // 293
    const int NBLK = (E + EPB - 1) / EPB;               // 245
    const int M = NB * NBLK;                            // 71785

    // Workspace layout (all written before read; no memsets needed):
    //   blkcnt[80000]  (>= M, 256B-aligned segments)
    //   dis[150080]  offsets[150080]  edata[E]
    //   yb[N*64 bf16]
    //   region R: zb[N*64 bf16], overlapped by pairs[E] (dead before agg1)
    int*   blkcnt  = (int*)d_ws;
    float* dis     = (float*)(blkcnt + 80000);
    int*   offsets = (int*)(dis + 150080);
    int*   edata   = offsets + 150080;
    unsigned short* yb = (unsigned short*)(edata + E);
    unsigned short* zb = yb + (size_t)N * EMB_DIM;
    unsigned int* pairs = (unsigned int*)zb;  // lifetime: C..D only
    float* out = (float*)d_out;

    bucket_hist<<<NBLK, 256, 0, stream>>>(cols, blkcnt, E, NB, NBLK);
    cursor_scan<<<1, 1024, 0, stream>>>(blkcnt, offsets, M, N, E);
    bucket_scatter<<<NBLK, 256, 0, stream>>>(rows, cols, blkcnt, pairs, E, NB, NBLK);
    bucket_finalize<<<NB, 1024, 0, stream>>>(pairs, blkcnt, edata, offsets, dis,
                                             N, E, NB, NBLK);

    int n4 = N * EMB_DIM / 4;
    toy_kernel<<<(n4 + 255) / 256, 256, 0, stream>>>(x, dis, yb, n4);

    int agg_blocks = (N + 3) / 4;  // 4 waves per 256-thread block
    // layer 1: yb -> zb (= dis^2 * sum y)
    agg_kernel<false><<<agg_blocks, 256, 0, stream>>>(yb, edata, offsets, dis,
                                                      nullptr, zb, nullptr, N);
    // layer 2 + final: out = (x + zb/dis + dis*sum zb[src]) / 3
    agg_kernel<true><<<agg_blocks, 256, 0, stream>>>(zb, edata, offsets, dis,
                                                     x, nullptr, out, N);
}

// Round 6
// 374.772 us; speedup vs baseline: 18.8410x; 1.1072x over previous
//
#include <hip/hip_runtime.h>
#include <hip/hip_bf16.h>

// SimGCL / LightGCN 2-layer propagation — round 5.
//   r4 -> r5:
//   - agg was gather-latency-bound (97us, 7.5 cy/cacheline/CU, VALU 43%):
//     inner loop now processes 16 edges/wave-iter (2 per 8-lane subgroup,
//     both gathers in flight) -> 2x memory-level parallelism.
//   - cursor_scan was a single block (1 CU) over 71785 ints; now a 3-kernel
//     parallel tile scan (71 blocks).
//   - toy_kernel (y = dis*x -> bf16) fused into bucket_finalize, which
//     already holds the per-col counts in LDS.
//   Pipeline: bucket_hist -> tile_sum -> tile_scan -> tile_rescan ->
//             bucket_scatter -> bucket_finalize(+y) -> agg1 -> agg2(final)

#define EMB_DIM 64
#define BUCKET_BITS 9
#define BUCKET_SZ 512
#define EPB 16384   // edges per partition block
#define NBMAX 512   // LDS capacity for bucket counters (NB = 293 actual)
#define ST 1024     // ints per scan tile

__device__ __forceinline__ float bf_lo(unsigned int q) { return __uint_as_float(q << 16); }
__device__ __forceinline__ float bf_hi(unsigned int q) { return __uint_as_float(q & 0xffff0000u); }
__device__ __forceinline__ unsigned int f2bf(float f) {  // RNE
    unsigned int u = __float_as_uint(f);
    return (u + 0x7fffu + ((u >> 16) & 1u)) >> 16;
}

// (A) per-block bucket histogram
__global__ void bucket_hist(const int* __restrict__ cols,
                            int* __restrict__ blkcnt, int E, int NB, int NBLK) {
    __shared__ int lh[NBMAX];
    int blk = blockIdx.x, t = threadIdx.x;
    for (int b = t; b < NB; b += blockDim.x) lh[b] = 0;
    __syncthreads();
    int start = blk * EPB, end = min(start + EPB, E);
    for (int i = start + t; i < end; i += blockDim.x)
        atomicAdd(&lh[cols[i] >> BUCKET_BITS], 1);
    __syncthreads();
    for (int b = t; b < NB; b += blockDim.x)
        blkcnt[b * NBLK + blk] = lh[b];
}

// (B1) per-tile sums of blkcnt
__global__ void tile_sum(const int* __restrict__ blkcnt,
                         int* __restrict__ tsum, int M) {
    __shared__ int red[4];
    int t = threadIdx.x;
    int base = blockIdx.x * ST + t * 4;
    int s = 0;
    if (base + 3 < M) {
        int4 v = *(const int4*)(blkcnt + base);
        s = v.x + v.y + v.z + v.w;
    } else {
        for (int i = 0; i < 4; ++i)
            if (base + i < M) s += blkcnt[base + i];
    }
    for (int off = 32; off; off >>= 1) s += __shfl_down(s, off);
    if ((t & 63) == 0) red[t >> 6] = s;
    __syncthreads();
    if (t == 0) tsum[blockIdx.x] = red[0] + red[1] + red[2] + red[3];
}

// (B2) scan tile sums (NT <= 128); also offsets[N] = E
__global__ void tile_scan(const int* __restrict__ tsum,
                          int* __restrict__ toff,
                          int* __restrict__ offsets, int NT, int N, int E) {
    __shared__ int lds[128];
    int t = threadIdx.x;
    int v = (t < NT) ? tsum[t] : 0;
    lds[t] = v;
    __syncthreads();
    for (int off = 1; off < 128; off <<= 1) {
        int u = (t >= off) ? lds[t - off] : 0;
        __syncthreads();
        lds[t] += u;
        __syncthreads();
    }
    if (t < NT) toff[t] = lds[t] - v;
    if (t == 0) offsets[N] = E;
}

// (B3) in-place exclusive scan of each tile with its offset
__global__ void tile_rescan(int* __restrict__ blkcnt,
                            const int* __restrict__ toff, int M) {
    __shared__ int lds[256];
    int t = threadIdx.x;
    int base = blockIdx.x * ST + t * 4;
    int c0 = 0, c1 = 0, c2 = 0, c3 = 0;
    if (base + 3 < M) {
        int4 v = *(const int4*)(blkcnt + base);
        c0 = v.x; c1 = v.y; c2 = v.z; c3 = v.w;
    } else {
        if (base + 0 < M) c0 = blkcnt[base + 0];
        if (base + 1 < M) c1 = blkcnt[base + 1];
        if (base + 2 < M) c2 = blkcnt[base + 2];
        if (base + 3 < M) c3 = blkcnt[base + 3];
    }
    int s = c0 + c1 + c2 + c3;
    lds[t] = s;
    __syncthreads();
    for (int off = 1; off < 256; off <<= 1) {
        int u = (t >= off) ? lds[t - off] : 0;
        __syncthreads();
        lds[t] += u;
        __syncthreads();
    }
    int run = toff[blockIdx.x] + lds[t] - s;
    if (base + 3 < M) {
        int4 o;
        o.x = run; run += c0;
        o.y = run; run += c1;
        o.z = run; run += c2;
        o.w = run; run += c3;
        *(int4*)(blkcnt + base) = o;
    } else {
        if (base + 0 < M) { blkcnt[base + 0] = run; run += c0; }
        if (base + 1 < M) { blkcnt[base + 1] = run; run += c1; }
        if (base + 2 < M) { blkcnt[base + 2] = run; run += c2; }
        if (base + 3 < M) { blkcnt[base + 3] = run; run += c3; }
    }
}

// (C) partition pass: write packed (src | lcol<<18) into bucket runs
__global__ void bucket_scatter(const int* __restrict__ rows,
                               const int* __restrict__ cols,
                               const int* __restrict__ cursor,
                               unsigned int* __restrict__ pairs,
                               int E, int NB, int NBLK) {
    __shared__ int lcur[NBMAX];
    __shared__ int lrank[NBMAX];
    int blk = blockIdx.x, t = threadIdx.x;
    for (int b = t; b < NB; b += blockDim.x) {
        lcur[b] = cursor[b * NBLK + blk];
        lrank[b] = 0;
    }
    __syncthreads();
    int start = blk * EPB, end = min(start + EPB, E);
    for (int i = start + t; i < end; i += blockDim.x) {
        int c = cols[i];
        int r = rows[i];
        int b = c >> BUCKET_BITS;
        int rk = atomicAdd(&lrank[b], 1);
        pairs[lcur[b] + rk] = (unsigned)r | ((unsigned)(c & (BUCKET_SZ - 1)) << 18);
    }
}

// (D) per-bucket finalize: counting sort by col; emits dis[], offsets[],
//     col-sorted src -> edata; ALSO converts this bucket's x rows to
//     y = dis*x in bf16 (fused toy pass).
__global__ void bucket_finalize(const unsigned int* __restrict__ pairs,
                                const int* __restrict__ cursor,
                                const float* __restrict__ x,
                                int* __restrict__ edata,
                                int* __restrict__ offsets,
                                float* __restrict__ dis,
                                unsigned short* __restrict__ yb,
                                int N, int E, int NB, int NBLK) {
    __shared__ int ccnt[BUCKET_SZ];
    __shared__ int cexc[BUCKET_SZ];
    __shared__ int sc[1024];
    int b = blockIdx.x, t = threadIdx.x;
    int base = cursor[b * NBLK];
    int end = (b + 1 < NB) ? cursor[(b + 1) * NBLK] : E;
    int col0 = b << BUCKET_BITS;
    int ncols = min(BUCKET_SZ, N - col0);

    if (t < BUCKET_SZ) ccnt[t] = 0;
    __syncthreads();
    for (int i = base + t; i < end; i += blockDim.x)
        atomicAdd(&ccnt[pairs[i] >> 18], 1);
    __syncthreads();

    int v = (t < BUCKET_SZ) ? ccnt[t] : 0;
    sc[t] = v;
    __syncthreads();
    for (int off = 1; off < 1024; off <<= 1) {
        int u = (t >= off) ? sc[t - off] : 0;
        __syncthreads();
        sc[t] += u;
        __syncthreads();
    }
    if (t < BUCKET_SZ) cexc[t] = sc[t] - v;
    __syncthreads();

    if (t < ncols) {
        int c = ccnt[t];
        offsets[col0 + t] = base + cexc[t];
        dis[col0 + t] = (c > 0) ? rsqrtf((float)c) : 0.0f;
    }
    // reuse sc[0..511] as rank counters
    if (t < BUCKET_SZ) sc[t] = 0;
    __syncthreads();
    for (int i = base + t; i < end; i += blockDim.x) {
        unsigned p = pairs[i];
        int lc = p >> 18;
        int src = p & 0x3FFFF;
        int rk = atomicAdd(&sc[lc], 1);
        edata[base + cexc[lc] + rk] = src;
    }

    // fused: y[row] = dis[row] * x[row] in bf16 for this bucket's rows.
    // ccnt[] is stable (unmodified since histogram). 16 uint2-chunks per row.
    for (int u = t; u < ncols * 16; u += blockDim.x) {
        int lr = u >> 4;
        int part = u & 15;
        int c = ccnt[lr];
        float d = (c > 0) ? rsqrtf((float)c) : 0.0f;
        size_t o = (((size_t)(col0 + lr)) << 6) + part * 4;
        float4 vx = *(const float4*)(x + o);
        uint2 w;
        w.x = f2bf(vx.x * d) | (f2bf(vx.y * d) << 16);
        w.y = f2bf(vx.z * d) | (f2bf(vx.w * d) << 16);
        *(uint2*)(yb + o) = w;
    }
}

__device__ __forceinline__ void acc8(float* acc, uint4 q) {
    acc[0] += bf_lo(q.x);
    acc[1] += bf_hi(q.x);
    acc[2] += bf_lo(q.y);
    acc[3] += bf_hi(q.y);
    acc[4] += bf_lo(q.z);
    acc[5] += bf_hi(q.z);
    acc[6] += bf_lo(q.w);
    acc[7] += bf_hi(q.w);
}

// Wave = 8 subgroups x 8 lanes; each sub owns TWO edges per iteration
// (16 edges / 16 gathers in flight per wave); lane holds 8 fp32 dims.
// !FINAL (embb = yb):  zb[c] = bf16( dis[c]^2 * acc )
//  FINAL (embb = zb):  out = (x + zb/dis + dis*acc)/3
template <bool FINAL>
__global__ void agg_kernel(const unsigned short* __restrict__ embb,
                           const int* __restrict__ edata,
                           const int* __restrict__ offsets,
                           const float* __restrict__ dis,
                           const float* __restrict__ x,        // FINAL only
                           unsigned short* __restrict__ outb,  // !FINAL
                           float* __restrict__ outf,           // FINAL
                           int n) {
    int wave = (blockIdx.x * blockDim.x + threadIdx.x) >> 6;
    int lane = threadIdx.x & 63;
    if (wave >= n) return;
    int sub = lane >> 3;
    int dimo = (lane & 7) * 8;

    int s = offsets[wave];
    int e = offsets[wave + 1];

    float acc[8] = {0, 0, 0, 0, 0, 0, 0, 0};

    for (int b = s; b < e; b += 16) {
        int i0 = b + sub;
        int i1 = i0 + 8;
        int s0 = (i0 < e) ? edata[i0] : -1;
        int s1 = (i1 < e) ? edata[i1] : -1;
        uint4 q0, q1;
        if (s0 >= 0) q0 = *(const uint4*)(embb + ((size_t)s0 << 6) + dimo);
        if (s1 >= 0) q1 = *(const uint4*)(embb + ((size_t)s1 << 6) + dimo);
        if (s0 >= 0) acc8(acc, q0);
        if (s1 >= 0) acc8(acc, q1);
    }

#pragma unroll
    for (int k = 0; k < 8; ++k) {
        acc[k] += __shfl_xor(acc[k], 8);
        acc[k] += __shfl_xor(acc[k], 16);
        acc[k] += __shfl_xor(acc[k], 32);
    }

    if (sub == 0) {
        float dc = dis[wave];
        size_t o = ((size_t)wave << 6) + dimo;
        if (FINAL) {
            float rd = (dc > 0.0f) ? 1.0f / dc : 0.0f;  // emb1 = z * rd
            float4 xa = *(const float4*)(x + o);
            float4 xc = *(const float4*)(x + o + 4);
            uint4 qz = *(const uint4*)(embb + o);  // own z (bf16)
            const float k3 = 1.0f / 3.0f;
            float4 r0, r1;
            r0.x = (xa.x + bf_lo(qz.x) * rd + dc * acc[0]) * k3;
            r0.y = (xa.y + bf_hi(qz.x) * rd + dc * acc[1]) * k3;
            r0.z = (xa.z + bf_lo(qz.y) * rd + dc * acc[2]) * k3;
            r0.w = (xa.w + bf_hi(qz.y) * rd + dc * acc[3]) * k3;
            r1.x = (xc.x + bf_lo(qz.z) * rd + dc * acc[4]) * k3;
            r1.y = (xc.y + bf_hi(qz.z) * rd + dc * acc[5]) * k3;
            r1.z = (xc.z + bf_lo(qz.w) * rd + dc * acc[6]) * k3;
            r1.w = (xc.w + bf_hi(qz.w) * rd + dc * acc[7]) * k3;
            *(float4*)(outf + o) = r0;
            *(float4*)(outf + o + 4) = r1;
        } else {
            float zs = dc * dc;  // z = dis^2 * acc
            uint4 q;
            q.x = f2bf(zs * acc[0]) | (f2bf(zs * acc[1]) << 16);
            q.y = f2bf(zs * acc[2]) | (f2bf(zs * acc[3]) << 16);
            q.z = f2bf(zs * acc[4]) | (f2bf(zs * acc[5]) << 16);
            q.w = f2bf(zs * acc[6]) | (f2bf(zs * acc[7]) << 16);
            *(uint4*)(outb + o) = q;
        }
    }
}

extern "C" void kernel_launch(void* const* d_in, const int* in_sizes, int n_in,
                              void* d_out, int out_size, void* d_ws, size_t ws_size,
                              hipStream_t stream) {
    const float* x  = (const float*)d_in[0];
    const int*   ei = (const int*)d_in[1];
    const int E = in_sizes[1] / 2;
    const int N = in_sizes[0] / EMB_DIM;  // 150000

    const int* rows = ei;       // edge_index[0]
    const int* cols = ei + E;   // edge_index[1]

    const int NB = (N + BUCKET_SZ - 1) >> BUCKET_BITS;  // 293
    const int NBLK = (E + EPB - 1) / EPB;               // 245
    const int M = NB * NBLK;                            // 71785
    const int NT = (M + ST - 1) / ST;                   // 71

    // Workspace layout:
    //   blkcnt[72000] tsum[128] toff[128] (pad to 80000 ints)
    //   dis[150080] offsets[150080] edata[E]
    //   yb[N*64 bf16]
    //   region R: zb[N*64 bf16] overlapped by pairs[E] (dead before agg1)
    int*   blkcnt  = (int*)d_ws;
    int*   tsum    = blkcnt + 72000;
    int*   toff    = tsum + 128;
    float* dis     = (float*)(blkcnt + 80000);
    int*   offsets = (int*)(dis + 150080);
    int*   edata   = offsets + 150080;
    unsigned short* yb = (unsigned short*)(edata + E);
    unsigned short* zb = yb + (size_t)N * EMB_DIM;
    unsigned int* pairs = (unsigned int*)zb;  // lifetime: C..D only
    float* out = (float*)d_out;

    bucket_hist<<<NBLK, 256, 0, stream>>>(cols, blkcnt, E, NB, NBLK);
    tile_sum<<<NT, 256, 0, stream>>>(blkcnt, tsum, M);
    tile_scan<<<1, 128, 0, stream>>>(tsum, toff, offsets, NT, N, E);
    tile_rescan<<<NT, 256, 0, stream>>>(blkcnt, toff, M);
    bucket_scatter<<<NBLK, 256, 0, stream>>>(rows, cols, blkcnt, pairs, E, NB, NBLK);
    bucket_finalize<<<NB, 1024, 0, stream>>>(pairs, blkcnt, x, edata, offsets,
                                             dis, yb, N, E, NB, NBLK);

    int agg_blocks = (N + 3) / 4;  // 4 waves per 256-thread block
    // layer 1: yb -> zb (= dis^2 * sum y)
    agg_kernel<false><<<agg_blocks, 256, 0, stream>>>(yb, edata, offsets, dis,
                                                      nullptr, zb, nullptr, N);
    // layer 2 + final: out = (x + zb/dis + dis*sum zb[src]) / 3
    agg_kernel<true><<<agg_blocks, 256, 0, stream>>>(zb, edata, offsets, dis,
                                                     x, nullptr, out, N);
}

// Round 7
// 358.463 us; speedup vs baseline: 19.6982x; 1.0455x over previous
//
#include <hip/hip_runtime.h>
#include <hip/hip_bf16.h>

// SimGCL / LightGCN 2-layer propagation — round 6.
//   r5 -> r6:
//   - Sort tail (6 kernels, ~210us) collapsed: fixed-capacity bucket
//     regions (CAP=16384/bucket ~= mean 13651 + 23 sigma) let one fused
//     kernel do LDS-hist -> global atomicAdd space reservation -> scatter
//     in a single pass (cols chunk re-read from L2). Replaces
//     hist+tile_sum+tile_scan+tile_rescan+scatter with init+fused_scatter
//     + a tiny 293-element bucket-base scan.
//   - agg: 4 edges per 8-lane subgroup (32 gathers in flight per wave).
//   Algebra (r4): y = dis*x (bf16); z[c] = dis[c]^2 * sum y[src];
//   out = (x + z/dis + dis * sum z[src]) / 3. No per-edge weights stored.

#define EMB_DIM 64
#define BUCKET_BITS 9
#define BUCKET_SZ 512
#define EPB 16384    // edges per partition block
#define NBMAX 512    // LDS capacity for bucket counters (NB = 293 actual)
#define CAP 16384    // per-bucket pairs capacity (mean 13651, sigma 117)

__device__ __forceinline__ float bf_lo(unsigned int q) { return __uint_as_float(q << 16); }
__device__ __forceinline__ float bf_hi(unsigned int q) { return __uint_as_float(q & 0xffff0000u); }
__device__ __forceinline__ unsigned int f2bf(float f) {  // RNE
    unsigned int u = __float_as_uint(f);
    return (u + 0x7fffu + ((u >> 16) & 1u)) >> 16;
}

// (0) init per-bucket cursors to region starts
__global__ void init_kernel(int* __restrict__ gcur, int NB) {
    int t = threadIdx.x;
    if (t < NB) gcur[t] = t * CAP;
}

// (1) fused partition: LDS hist -> global reserve -> scatter, one kernel.
__global__ void fused_scatter(const int* __restrict__ rows,
                              const int* __restrict__ cols,
                              int* __restrict__ gcur,
                              unsigned int* __restrict__ pairs,
                              int E, int NB) {
    __shared__ int lh[NBMAX];
    __shared__ int lbase[NBMAX];
    __shared__ int lrank[NBMAX];
    int blk = blockIdx.x, t = threadIdx.x;
    for (int b = t; b < NB; b += blockDim.x) lh[b] = 0;
    __syncthreads();
    int start = blk * EPB, end = min(start + EPB, E);
    for (int i = start + t; i < end; i += blockDim.x)
        atomicAdd(&lh[cols[i] >> BUCKET_BITS], 1);
    __syncthreads();
    for (int b = t; b < NB; b += blockDim.x) {
        int c = lh[b];
        lbase[b] = c ? atomicAdd(&gcur[b], c) : 0;
        lrank[b] = 0;
    }
    __syncthreads();
    for (int i = start + t; i < end; i += blockDim.x) {
        int c = cols[i];              // L2-hot re-read
        int r = rows[i];
        int b = c >> BUCKET_BITS;
        int rk = atomicAdd(&lrank[b], 1);
        pairs[lbase[b] + rk] = (unsigned)r | ((unsigned)(c & (BUCKET_SZ - 1)) << 18);
    }
}

// (2) scan bucket counts (NB <= 512) -> gbase (exclusive, for edata);
//     also offsets[N] = E.
__global__ void count_scan(const int* __restrict__ gcur,
                           int* __restrict__ gbase,
                           int* __restrict__ offsets, int NB, int N, int E) {
    __shared__ int lds[NBMAX];
    int t = threadIdx.x;
    int v = (t < NB) ? (gcur[t] - t * CAP) : 0;
    lds[t] = v;
    __syncthreads();
    for (int off = 1; off < NBMAX; off <<= 1) {
        int u = (t >= off) ? lds[t - off] : 0;
        __syncthreads();
        lds[t] += u;
        __syncthreads();
    }
    if (t < NB) gbase[t] = lds[t] - v;
    if (t == 0) offsets[N] = E;
}

// (3) per-bucket finalize: counting sort by col; emits dis[], offsets[],
//     col-sorted src -> edata; fused y = dis*x -> bf16 for bucket's rows.
__global__ void bucket_finalize(const unsigned int* __restrict__ pairs,
                                const int* __restrict__ gcur,
                                const int* __restrict__ gbase,
                                const float* __restrict__ x,
                                int* __restrict__ edata,
                                int* __restrict__ offsets,
                                float* __restrict__ dis,
                                unsigned short* __restrict__ yb,
                                int N, int E, int NB) {
    __shared__ int ccnt[BUCKET_SZ];
    __shared__ int cexc[BUCKET_SZ];
    __shared__ int sc[1024];
    int b = blockIdx.x, t = threadIdx.x;
    int pbase = b * CAP;
    int cnt = gcur[b] - pbase;
    int base = gbase[b];
    int col0 = b << BUCKET_BITS;
    int ncols = min(BUCKET_SZ, N - col0);

    if (t < BUCKET_SZ) ccnt[t] = 0;
    __syncthreads();
    for (int i = t; i < cnt; i += blockDim.x)
        atomicAdd(&ccnt[pairs[pbase + i] >> 18], 1);
    __syncthreads();

    int v = (t < BUCKET_SZ) ? ccnt[t] : 0;
    sc[t] = v;
    __syncthreads();
    for (int off = 1; off < 1024; off <<= 1) {
        int u = (t >= off) ? sc[t - off] : 0;
        __syncthreads();
        sc[t] += u;
        __syncthreads();
    }
    if (t < BUCKET_SZ) cexc[t] = sc[t] - v;
    __syncthreads();

    if (t < ncols) {
        int c = ccnt[t];
        offsets[col0 + t] = base + cexc[t];
        dis[col0 + t] = (c > 0) ? rsqrtf((float)c) : 0.0f;
    }
    // reuse sc[0..511] as rank counters
    if (t < BUCKET_SZ) sc[t] = 0;
    __syncthreads();
    for (int i = t; i < cnt; i += blockDim.x) {
        unsigned p = pairs[pbase + i];
        int lc = p >> 18;
        int src = p & 0x3FFFF;
        int rk = atomicAdd(&sc[lc], 1);
        edata[base + cexc[lc] + rk] = src;
    }

    // fused: y[row] = dis[row] * x[row] in bf16 (ccnt stable).
    for (int u = t; u < ncols * 16; u += blockDim.x) {
        int lr = u >> 4;
        int part = u & 15;
        int c = ccnt[lr];
        float d = (c > 0) ? rsqrtf((float)c) : 0.0f;
        size_t o = (((size_t)(col0 + lr)) << 6) + part * 4;
        float4 vx = *(const float4*)(x + o);
        uint2 w;
        w.x = f2bf(vx.x * d) | (f2bf(vx.y * d) << 16);
        w.y = f2bf(vx.z * d) | (f2bf(vx.w * d) << 16);
        *(uint2*)(yb + o) = w;
    }
}

__device__ __forceinline__ void acc8(float* acc, uint4 q) {
    acc[0] += bf_lo(q.x);
    acc[1] += bf_hi(q.x);
    acc[2] += bf_lo(q.y);
    acc[3] += bf_hi(q.y);
    acc[4] += bf_lo(q.z);
    acc[5] += bf_hi(q.z);
    acc[6] += bf_lo(q.w);
    acc[7] += bf_hi(q.w);
}

// Wave = 8 subgroups x 8 lanes; each sub owns FOUR edges per iteration
// (32 edges / 32 gathers in flight per wave); lane holds 8 fp32 dims.
// !FINAL (embb = yb):  zb[c] = bf16( dis[c]^2 * acc )
//  FINAL (embb = zb):  out = (x + zb/dis + dis*acc)/3
template <bool FINAL>
__global__ void agg_kernel(const unsigned short* __restrict__ embb,
                           const int* __restrict__ edata,
                           const int* __restrict__ offsets,
                           const float* __restrict__ dis,
                           const float* __restrict__ x,        // FINAL only
                           unsigned short* __restrict__ outb,  // !FINAL
                           float* __restrict__ outf,           // FINAL
                           int n) {
    int wave = (blockIdx.x * blockDim.x + threadIdx.x) >> 6;
    int lane = threadIdx.x & 63;
    if (wave >= n) return;
    int sub = lane >> 3;
    int dimo = (lane & 7) * 8;

    int s = offsets[wave];
    int e = offsets[wave + 1];

    float acc[8] = {0, 0, 0, 0, 0, 0, 0, 0};

    for (int b = s; b < e; b += 32) {
        int i0 = b + sub;
        int i1 = i0 + 8;
        int i2 = i0 + 16;
        int i3 = i0 + 24;
        int s0 = (i0 < e) ? edata[i0] : -1;
        int s1 = (i1 < e) ? edata[i1] : -1;
        int s2 = (i2 < e) ? edata[i2] : -1;
        int s3 = (i3 < e) ? edata[i3] : -1;
        uint4 q0, q1, q2, q3;
        if (s0 >= 0) q0 = *(const uint4*)(embb + ((size_t)s0 << 6) + dimo);
        if (s1 >= 0) q1 = *(const uint4*)(embb + ((size_t)s1 << 6) + dimo);
        if (s2 >= 0) q2 = *(const uint4*)(embb + ((size_t)s2 << 6) + dimo);
        if (s3 >= 0) q3 = *(const uint4*)(embb + ((size_t)s3 << 6) + dimo);
        if (s0 >= 0) acc8(acc, q0);
        if (s1 >= 0) acc8(acc, q1);
        if (s2 >= 0) acc8(acc, q2);
        if (s3 >= 0) acc8(acc, q3);
    }

#pragma unroll
    for (int k = 0; k < 8; ++k) {
        acc[k] += __shfl_xor(acc[k], 8);
        acc[k] += __shfl_xor(acc[k], 16);
        acc[k] += __shfl_xor(acc[k], 32);
    }

    if (sub == 0) {
        float dc = dis[wave];
        size_t o = ((size_t)wave << 6) + dimo;
        if (FINAL) {
            float rd = (dc > 0.0f) ? 1.0f / dc : 0.0f;  // emb1 = z * rd
            float4 xa = *(const float4*)(x + o);
            float4 xc = *(const float4*)(x + o + 4);
            uint4 qz = *(const uint4*)(embb + o);  // own z (bf16)
            const float k3 = 1.0f / 3.0f;
            float4 r0, r1;
            r0.x = (xa.x + bf_lo(qz.x) * rd + dc * acc[0]) * k3;
            r0.y = (xa.y + bf_hi(qz.x) * rd + dc * acc[1]) * k3;
            r0.z = (xa.z + bf_lo(qz.y) * rd + dc * acc[2]) * k3;
            r0.w = (xa.w + bf_hi(qz.y) * rd + dc * acc[3]) * k3;
            r1.x = (xc.x + bf_lo(qz.z) * rd + dc * acc[4]) * k3;
            r1.y = (xc.y + bf_hi(qz.z) * rd + dc * acc[5]) * k3;
            r1.z = (xc.z + bf_lo(qz.w) * rd + dc * acc[6]) * k3;
            r1.w = (xc.w + bf_hi(qz.w) * rd + dc * acc[7]) * k3;
            *(float4*)(outf + o) = r0;
            *(float4*)(outf + o + 4) = r1;
        } else {
            float zs = dc * dc;  // z = dis^2 * acc
            uint4 q;
            q.x = f2bf(zs * acc[0]) | (f2bf(zs * acc[1]) << 16);
            q.y = f2bf(zs * acc[2]) | (f2bf(zs * acc[3]) << 16);
            q.z = f2bf(zs * acc[4]) | (f2bf(zs * acc[5]) << 16);
            q.w = f2bf(zs * acc[6]) | (f2bf(zs * acc[7]) << 16);
            *(uint4*)(outb + o) = q;
        }
    }
}

extern "C" void kernel_launch(void* const* d_in, const int* in_sizes, int n_in,
                              void* d_out, int out_size, void* d_ws, size_t ws_size,
                              hipStream_t stream) {
    const float* x  = (const float*)d_in[0];
    const int*   ei = (const int*)d_in[1];
    const int E = in_sizes[1] / 2;
    const int N = in_sizes[0] / EMB_DIM;  // 150000

    const int* rows = ei;       // edge_index[0]
    const int* cols = ei + E;   // edge_index[1]

    const int NB = (N + BUCKET_SZ - 1) >> BUCKET_BITS;  // 293
    const int NBLK = (E + EPB - 1) / EPB;               // 245

    // Workspace layout (ints):
    //   gcur[512] gbase[512]
    //   dis[150080] offsets[150080] edata[E]
    //   yb[N*64 bf16] = 4.8M ints
    //   region R: zb[N*64 bf16] overlapped by pairs[NB*CAP] (dead before agg1)
    int*   gcur    = (int*)d_ws;
    int*   gbase   = gcur + 512;
    float* dis     = (float*)(gbase + 512);
    int*   offsets = (int*)(dis + 150080);
    int*   edata   = offsets + 150080;
    unsigned short* yb = (unsigned short*)(edata + E);
    unsigned short* zb = yb + (size_t)N * EMB_DIM;
    unsigned int* pairs = (unsigned int*)zb;  // lifetime: fused_scatter..finalize
    float* out = (float*)d_out;

    init_kernel<<<1, 512, 0, stream>>>(gcur, NB);
    fused_scatter<<<NBLK, 256, 0, stream>>>(rows, cols, gcur, pairs, E, NB);
    count_scan<<<1, 512, 0, stream>>>(gcur, gbase, offsets, NB, N, E);
    bucket_finalize<<<NB, 1024, 0, stream>>>(pairs, gcur, gbase, x, edata,
                                             offsets, dis, yb, N, E, NB);

    int agg_blocks = (N + 3) / 4;  // 4 waves per 256-thread block
    // layer 1: yb -> zb (= dis^2 * sum y)
    agg_kernel<false><<<agg_blocks, 256, 0, stream>>>(yb, edata, offsets, dis,
                                                      nullptr, zb, nullptr, N);
    // layer 2 + final: out = (x + zb/dis + dis*sum zb[src]) / 3
    agg_kernel<true><<<agg_blocks, 256, 0, stream>>>(zb, edata, offsets, dis,
                                                     x, nullptr, out, N);
}